// Round 5
// baseline (47.183 us; speedup 1.0000x reference)
//
#include <hip/hip_runtime.h>

// QDFRCell fused: out = fq(relu(fq(xq*qmask,0,2) + prev - fq(0.2*prev,0,2)), 0, 2)
// x:[16384,1] f32, prev:[16384,2048] f32, mask:[1,2048] f32 -> out:[16384,2048] f32
// Round 4: 45.1 us = 5.95 TB/s mixed (94.6% of 6.29 TB/s copy ceiling).
// Round 5 experiment (last cache-policy lever): keep the WRITE stream
// resident instead of the read stream. prev -> NT loads (stream, don't
// allocate); out -> temporal stores (write-allocate; dirty lines re-dirtied
// in place across graph replays, so HBM writeback per replay collapses).
// Win: ~25-32 us, warm WRITE_SIZE << 134 MB. Null: ~45 us -> mixed-stream
// roofline confirmed (L3 is memory-side, ignores nt hints).

constexpr int NN  = 2048;
constexpr int N4  = NN / 4;          // 512 float4 per row
constexpr int RPB = 8;               // rows per block

typedef float vf4 __attribute__((ext_vector_type(4)));

__global__ __launch_bounds__(512) void qdfr_fused(const float* __restrict__ x,
                                                  const float* __restrict__ prev,
                                                  const float* __restrict__ mask,
                                                  float* __restrict__ out) {
    constexpr float IN_SCALE = 0.497f / 255.0f;
    constexpr float INV_IN   = 1.0f / (0.497f / 255.0f);
    constexpr float L_SCALE  = 2.0f / 255.0f;
    constexpr float INV_L    = 1.0f / (2.0f / 255.0f);

    const int t    = threadIdx.x;
    const int row0 = blockIdx.x * RPB;

    // Non-temporal loads — prev streams through without evicting out's lines.
    vf4 p[RPB];
    #pragma unroll
    for (int r = 0; r < RPB; ++r)
        p[r] = __builtin_nontemporal_load((const vf4*)prev + (long)(row0 + r) * N4 + t);

    // Thread t consumes exactly mask4[t]; same registers feed the reduction.
    const vf4 m = ((const vf4*)mask)[t];

    float mn = fminf(fminf(m.x, m.y), fminf(m.z, m.w));
    float mx = fmaxf(fmaxf(m.x, m.y), fmaxf(m.z, m.w));
    #pragma unroll
    for (int d = 1; d < 64; d <<= 1) {
        mn = fminf(mn, __shfl_xor(mn, d));
        mx = fmaxf(mx, __shfl_xor(mx, d));
    }
    __shared__ float red[16];
    const int wave = t >> 6;
    if ((t & 63) == 0) { red[wave * 2] = mn; red[wave * 2 + 1] = mx; }
    __syncthreads();
    mn = red[0];
    mx = red[1];
    #pragma unroll
    for (int w = 1; w < 8; ++w) {
        mn = fminf(mn, red[w * 2]);
        mx = fmaxf(mx, red[w * 2 + 1]);
    }

    const float mscale = (mx - mn) / 255.0f;   // bit-exact vs reference expr
    const float minv   = 1.0f / mscale;

    // Quantize this thread's mask element once (shared by all 8 rows).
    vf4 qm;
    qm.x = rintf((m.x - mn) * minv) * mscale + mn;
    qm.y = rintf((m.y - mn) * minv) * mscale + mn;
    qm.z = rintf((m.z - mn) * minv) * mscale + mn;
    qm.w = rintf((m.w - mn) * minv) * mscale + mn;

    #pragma unroll
    for (int r = 0; r < RPB; ++r) {
        // fake_quant(x[row], 0, 0.497) — block-uniform scalar
        const float xv = x[row0 + r];
        const float xc = fminf(fmaxf(xv, 0.0f), 0.497f);
        const float xq = rintf(xc * INV_IN) * IN_SCALE;

        vf4 o;
#define COMP(c)                                                                \
        {                                                                      \
            const float vec = xq * qm.c;                                       \
            const float vcl = fminf(fmaxf(vec, 0.0f), 2.0f);                   \
            const float vq  = rintf(vcl * INV_L) * L_SCALE;                    \
            const float bcl = fminf(fmaxf(0.2f * p[r].c, 0.0f), 2.0f);         \
            const float bq  = rintf(bcl * INV_L) * L_SCALE;                    \
            const float rl  = fmaxf(vq + p[r].c - bq, 0.0f); /* relu */        \
            o.c = rintf(fminf(rl, 2.0f) * INV_L) * L_SCALE;  /* rl >= 0 */     \
        }
        COMP(x) COMP(y) COMP(z) COMP(w)
#undef COMP
        // Temporal store — let out write-allocate and stay dirty in cache
        // across replays; HBM writeback then happens at most once per line.
        ((vf4*)out)[(long)(row0 + r) * N4 + t] = o;
    }
}

extern "C" void kernel_launch(void* const* d_in, const int* in_sizes, int n_in,
                              void* d_out, int out_size, void* d_ws, size_t ws_size,
                              hipStream_t stream) {
    const float* x    = (const float*)d_in[0];   // [16384,1]
    const float* prev = (const float*)d_in[1];   // [16384,2048]
    const float* mask = (const float*)d_in[2];   // [1,2048]
    float* out = (float*)d_out;

    const int rows = in_sizes[1] / NN;           // 16384
    qdfr_fused<<<rows / RPB, 512, 0, stream>>>(x, prev, mask, out);
}

// Round 6
// 45.302 us; speedup vs baseline: 1.0415x; 1.0415x over previous
//
#include <hip/hip_runtime.h>

// QDFRCell fused: out = fq(relu(fq(xq*qmask,0,2) + prev - fq(0.2*prev,0,2)), 0, 2)
// x:[16384,1] f32, prev:[16384,2048] f32, mask:[1,2048] f32 -> out:[16384,2048] f32
//
// FINAL (round-4 config, best measured): temporal prev loads + NT out stores.
// 45.1 us = 268.4 MB / 45.1 us = 5.95 TB/s mixed = 94.6% of the 6.29 TB/s
// measured copy ceiling. Cache-policy space mapped:
//   NT/NT 48.5 | temporal/NT 45.1 (best) | NT/temporal 47.2
// Traffic is compulsory (prev read + out write, bit-exact absmax=0.0);
// compute fully hidden (VALUBusy ~5%). This is the mixed-stream roofline.

constexpr int NN  = 2048;
constexpr int N4  = NN / 4;          // 512 float4 per row
constexpr int RPB = 8;               // rows per block

typedef float vf4 __attribute__((ext_vector_type(4)));

__global__ __launch_bounds__(512) void qdfr_fused(const float* __restrict__ x,
                                                  const float* __restrict__ prev,
                                                  const float* __restrict__ mask,
                                                  float* __restrict__ out) {
    constexpr float IN_SCALE = 0.497f / 255.0f;
    constexpr float INV_IN   = 1.0f / (0.497f / 255.0f);
    constexpr float L_SCALE  = 2.0f / 255.0f;
    constexpr float INV_L    = 1.0f / (2.0f / 255.0f);

    const int t    = threadIdx.x;
    const int row0 = blockIdx.x * RPB;

    // Temporal loads for prev (best measured); all 8 issued up front for MLP.
    vf4 p[RPB];
    #pragma unroll
    for (int r = 0; r < RPB; ++r)
        p[r] = ((const vf4*)prev)[(long)(row0 + r) * N4 + t];

    // Thread t consumes exactly mask4[t]; same registers feed the reduction.
    const vf4 m = ((const vf4*)mask)[t];

    float mn = fminf(fminf(m.x, m.y), fminf(m.z, m.w));
    float mx = fmaxf(fmaxf(m.x, m.y), fmaxf(m.z, m.w));
    #pragma unroll
    for (int d = 1; d < 64; d <<= 1) {
        mn = fminf(mn, __shfl_xor(mn, d));
        mx = fmaxf(mx, __shfl_xor(mx, d));
    }
    __shared__ float red[16];
    const int wave = t >> 6;
    if ((t & 63) == 0) { red[wave * 2] = mn; red[wave * 2 + 1] = mx; }
    __syncthreads();
    mn = red[0];
    mx = red[1];
    #pragma unroll
    for (int w = 1; w < 8; ++w) {
        mn = fminf(mn, red[w * 2]);
        mx = fmaxf(mx, red[w * 2 + 1]);
    }

    const float mscale = (mx - mn) / 255.0f;   // bit-exact vs reference expr
    const float minv   = 1.0f / mscale;

    // Quantize this thread's mask element once (shared by all 8 rows).
    vf4 qm;
    qm.x = rintf((m.x - mn) * minv) * mscale + mn;
    qm.y = rintf((m.y - mn) * minv) * mscale + mn;
    qm.z = rintf((m.z - mn) * minv) * mscale + mn;
    qm.w = rintf((m.w - mn) * minv) * mscale + mn;

    #pragma unroll
    for (int r = 0; r < RPB; ++r) {
        // fake_quant(x[row], 0, 0.497) — block-uniform scalar
        const float xv = x[row0 + r];
        const float xc = fminf(fmaxf(xv, 0.0f), 0.497f);
        const float xq = rintf(xc * INV_IN) * IN_SCALE;

        vf4 o;
#define COMP(c)                                                                \
        {                                                                      \
            const float vec = xq * qm.c;                                       \
            const float vcl = fminf(fmaxf(vec, 0.0f), 2.0f);                   \
            const float vq  = rintf(vcl * INV_L) * L_SCALE;                    \
            const float bcl = fminf(fmaxf(0.2f * p[r].c, 0.0f), 2.0f);         \
            const float bq  = rintf(bcl * INV_L) * L_SCALE;                    \
            const float rl  = fmaxf(vq + p[r].c - bq, 0.0f); /* relu */        \
            o.c = rintf(fminf(rl, 2.0f) * INV_L) * L_SCALE;  /* rl >= 0 */     \
        }
        COMP(x) COMP(y) COMP(z) COMP(w)
#undef COMP
        // NT store — keep the 134 MB write stream from evicting prev.
        __builtin_nontemporal_store(o, (vf4*)out + (long)(row0 + r) * N4 + t);
    }
}

extern "C" void kernel_launch(void* const* d_in, const int* in_sizes, int n_in,
                              void* d_out, int out_size, void* d_ws, size_t ws_size,
                              hipStream_t stream) {
    const float* x    = (const float*)d_in[0];   // [16384,1]
    const float* prev = (const float*)d_in[1];   // [16384,2048]
    const float* mask = (const float*)d_in[2];   // [1,2048]
    float* out = (float*)d_out;

    const int rows = in_sizes[1] / NN;           // 16384
    qdfr_fused<<<rows / RPB, 512, 0, stream>>>(x, prev, mask, out);
}